// Round 6
// baseline (195.089 us; speedup 1.0000x reference)
//
#include <hip/hip_runtime.h>

typedef unsigned short ushort_t;
typedef __bf16 bf16x8 __attribute__((ext_vector_type(8)));
typedef unsigned short ushortx8 __attribute__((ext_vector_type(8)));
typedef unsigned short ushortx4 __attribute__((ext_vector_type(4)));
typedef unsigned int uintx2 __attribute__((ext_vector_type(2)));
typedef float floatx4 __attribute__((ext_vector_type(4)));

__device__ inline void load16_lds(const ushort_t* g, ushort_t* l) {
  __builtin_amdgcn_global_load_lds(
      (__attribute__((address_space(1))) void*)(g),
      (__attribute__((address_space(3))) void*)(l),
      16, 0, 0);
}

__device__ inline float bf2f(ushort_t u) {
  unsigned int v = ((unsigned int)u) << 16;
  return __builtin_bit_cast(float, v);
}

__device__ inline ushort_t f2bf(float f) {
  unsigned int u = __builtin_bit_cast(unsigned int, f);
  u += 0x7fffu + ((u >> 16) & 1u);
  return (ushort_t)(u >> 16);
}

__device__ inline bf16x8 ldfrag(const ushort_t* p) {
  return __builtin_bit_cast(bf16x8, *(const ushortx8*)p);
}

// ---------------------------------------------------------------------------
// dtype sniffer: flag=1 -> fp32 inputs, flag=0 -> bf16 inputs.
// ---------------------------------------------------------------------------
__global__ __launch_bounds__(256) void sniff_dtype(const ushort_t* __restrict__ x,
                                                   int* __restrict__ flag) {
  __shared__ float red[256];
  float m = 0.f;
  for (int i = threadIdx.x; i < 8192; i += 256) {
    float v = fabsf(bf2f(x[i]));
    if (!(v < 1e4f)) v = 1e30f;
    m = fmaxf(m, v);
  }
  red[threadIdx.x] = m;
  __syncthreads();
  for (int s = 128; s > 0; s >>= 1) {
    if (threadIdx.x < s) red[threadIdx.x] = fmaxf(red[threadIdx.x], red[threadIdx.x + s]);
    __syncthreads();
  }
  if (threadIdx.x == 0) *flag = (red[0] > 1e4f) ? 1 : 0;
}

// ---------------------------------------------------------------------------
// Canonicalize inputs to bf16 (x, Wq, Wk, Wv) and fp32 biases.
// ---------------------------------------------------------------------------
__global__ __launch_bounds__(256) void convert_all(
    const void* __restrict__ x,
    const void* __restrict__ wq, const void* __restrict__ wk, const void* __restrict__ wv,
    const void* __restrict__ bq, const void* __restrict__ bk, const void* __restrict__ bv,
    ushort_t* __restrict__ xb, ushort_t* __restrict__ wqb,
    ushort_t* __restrict__ wkb, ushort_t* __restrict__ wvb,
    float* __restrict__ biasf, const int* __restrict__ flag)
{
  const bool f32 = (*flag != 0);
  const int seg = blockIdx.y;
  if (seg == 4) {
    const int i = blockIdx.x * 256 + threadIdx.x;
    if (i >= 1024) return;
    const void* bs[3] = {bq, bk, bv};
#pragma unroll
    for (int k = 0; k < 3; ++k)
      biasf[k * 1024 + i] = f32 ? ((const float*)bs[k])[i] : bf2f(((const ushort_t*)bs[k])[i]);
    return;
  }
  const void* src = (seg == 0) ? x : (seg == 1) ? wq : (seg == 2) ? wk : wv;
  ushort_t* dst   = (seg == 0) ? xb : (seg == 1) ? wqb : (seg == 2) ? wkb : wvb;
  const int n = (seg == 0) ? 4194304 : 1048576;
  const int i = (blockIdx.x * 256 + threadIdx.x) * 8;
  if (i >= n) return;
  if (f32) {
    const float* s = (const float*)src + i;
    ushortx8 o;
#pragma unroll
    for (int j = 0; j < 8; ++j) o[j] = f2bf(s[j]);
    *(ushortx8*)(dst + i) = o;
  } else {
    *(ushortx8*)(dst + i) = *(const ushortx8*)((const ushort_t*)src + i);
  }
}

// ---------------------------------------------------------------------------
// QKV projection: out = x @ W^T + b; Q scaled by log2(e)/sqrt(64).
// which==2 (V) writes DIRECTLY in transposed layout Vt(bh,hs,s).
// ---------------------------------------------------------------------------
__global__ __launch_bounds__(256, 2) void qkv_gemm(
    const ushort_t* __restrict__ x,
    const ushort_t* __restrict__ Wq, const ushort_t* __restrict__ Wk,
    const ushort_t* __restrict__ Wv, const float* __restrict__ biasf,
    ushort_t* __restrict__ Qo, ushort_t* __restrict__ Ko, ushort_t* __restrict__ Vt)
{
  __shared__ __attribute__((aligned(16))) ushort_t As[128 * 32];
  __shared__ __attribute__((aligned(16))) ushort_t Bs[128 * 32];

  const int which = blockIdx.z;
  const ushort_t* W = (which == 0) ? Wq : (which == 1) ? Wk : Wv;
  const float oscale = (which == 0) ? 0.18033688011112042f : 1.0f;

  const int n0 = blockIdx.x * 128;
  const int m0 = blockIdx.y * 128;

  const int tid  = threadIdx.x;
  const int wave = tid >> 6;
  const int lane = tid & 63;
  const int ln   = lane & 15;
  const int quad = lane >> 4;
  const int wm = (wave >> 1) * 64;
  const int wn = (wave & 1) * 64;

  floatx4 acc[4][4];
#pragma unroll
  for (int i = 0; i < 4; ++i)
#pragma unroll
    for (int j = 0; j < 4; ++j) acc[i][j] = floatx4{0.f, 0.f, 0.f, 0.f};

  const int c1 = tid, c2 = tid + 256;
  const ushort_t* ga1 = x + (m0 + (c1 >> 2)) * 1024 + (c1 & 3) * 8;
  const ushort_t* ga2 = x + (m0 + (c2 >> 2)) * 1024 + (c2 & 3) * 8;
  const ushort_t* gb1 = W + (n0 + (c1 >> 2)) * 1024 + (c1 & 3) * 8;
  const ushort_t* gb2 = W + (n0 + (c2 >> 2)) * 1024 + (c2 & 3) * 8;
  ushort_t* la1 = As + wave * 512;
  ushort_t* la2 = As + 2048 + wave * 512;
  ushort_t* lb1 = Bs + wave * 512;
  ushort_t* lb2 = Bs + 2048 + wave * 512;

  for (int kt = 0; kt < 1024; kt += 32) {
    __syncthreads();
    load16_lds(ga1 + kt, la1);
    load16_lds(ga2 + kt, la2);
    load16_lds(gb1 + kt, lb1);
    load16_lds(gb2 + kt, lb2);
    __syncthreads();

    bf16x8 af[4], bfr[4];
#pragma unroll
    for (int mi = 0; mi < 4; ++mi)
      af[mi] = ldfrag(As + (wm + mi * 16 + ln) * 32 + quad * 8);
#pragma unroll
    for (int ni = 0; ni < 4; ++ni)
      bfr[ni] = ldfrag(Bs + (wn + ni * 16 + ln) * 32 + quad * 8);
#pragma unroll
    for (int mi = 0; mi < 4; ++mi)
#pragma unroll
      for (int ni = 0; ni < 4; ++ni)
        acc[mi][ni] = __builtin_amdgcn_mfma_f32_16x16x32_bf16(af[mi], bfr[ni], acc[mi][ni], 0, 0, 0);
  }

  float bvv[4];
#pragma unroll
  for (int ni = 0; ni < 4; ++ni) bvv[ni] = biasf[which * 1024 + n0 + wn + ni * 16 + ln];

  if (which == 2) {
#pragma unroll
    for (int mi = 0; mi < 4; ++mi)
#pragma unroll
      for (int ni = 0; ni < 4; ++ni) {
        const int col = n0 + wn + ni * 16 + ln;
        const int row0 = m0 + wm + mi * 16 + quad * 4;
        const int b = row0 >> 11, s0 = row0 & 2047;
        const int h = col >> 6, hs = col & 63;
        ushortx4 pk;
#pragma unroll
        for (int r = 0; r < 4; ++r) pk[r] = f2bf(acc[mi][ni][r] + bvv[ni]);
        *(ushortx4*)(Vt + ((size_t)((b * 16 + h) * 64 + hs)) * 2048 + s0) = pk;
      }
  } else {
    ushort_t* out = (which == 0) ? Qo : Ko;
#pragma unroll
    for (int mi = 0; mi < 4; ++mi)
#pragma unroll
      for (int ni = 0; ni < 4; ++ni) {
        const int col = n0 + wn + ni * 16 + ln;
#pragma unroll
        for (int r = 0; r < 4; ++r) {
          const int row = m0 + wm + mi * 16 + quad * 4 + r;
          out[row * 1024 + col] = f2bf((acc[mi][ni][r] + bvv[ni]) * oscale);
        }
      }
  }
}

// ---------------------------------------------------------------------------
// Flash attention v4 — work-balanced 4-wave blocks, causal.
// Block = 256 thr (4 waves), handles the q-chunk PAIR (63-pr, pr) in two
// sequential phases; in each phase all 4 waves split kv-tiles (t += 4) and
// partials combine additively (no-max softmax). Per-wave work is
// ((c+2) + (65-c))/4 ~= 16.75 tiles for EVERY wave in EVERY block ->
// constant block makespan, 16 waves/CU live for the whole kernel.
// Inner loop body identical to the verified flash3b.
// LDS: Ps (4 x 4.6KB) unioned with combine buffer Cb (3 x 8.7KB) + lbuf.
// ---------------------------------------------------------------------------
__global__ __launch_bounds__(256) void flash4(
    const ushort_t* __restrict__ Q, const ushort_t* __restrict__ Kx,
    const ushort_t* __restrict__ Vt, void* __restrict__ out,
    const int* __restrict__ flag)
{
  __shared__ __attribute__((aligned(16))) char smem[27648];

  const bool f32o = (*flag != 0);
  const int tid  = threadIdx.x;
  const int wave = tid >> 6;
  const int lane = tid & 63;
  const int ln = lane & 15, quad = lane >> 4;

  const int i = blockIdx.x;
  const int xcd = i & 7, j = i >> 3;
  const int bh = xcd * 4 + (j & 3);
  const int pr = j >> 2;                 // 0..31
  const int b = bh >> 4, h = bh & 15;

  const ushort_t* kbase = Kx + ((size_t)b * 2048) * 1024 + h * 64;
  const ushort_t* vbase = Vt + (size_t)bh * 64 * 2048;
  ushort_t* Pw = (ushort_t*)smem + wave * 2304;   // 32 x 72, +16B row pad
  float* Cb = (float*)smem;                        // 3 x 32 x 68 (union w/ Ps)
  float* lb = (float*)(smem + 26112);              // 3 x 64 x 2

  for (int phase = 0; phase < 2; ++phase) {
    const int c = phase ? pr : (63 - pr);          // big chunk first
    const int qw = c * 32;
    const int ntiles = (c + 2) >> 1;

    bf16x8 qf[2][2];
#pragma unroll
    for (int bi = 0; bi < 2; ++bi)
#pragma unroll
      for (int ks = 0; ks < 2; ++ks)
        qf[bi][ks] = ldfrag(Q + (size_t)(b * 2048 + qw + bi * 16 + ln) * 1024 + h * 64 + ks * 32 + quad * 8);

    floatx4 ot[4][2];
#pragma unroll
    for (int ai = 0; ai < 4; ++ai)
#pragma unroll
      for (int bi = 0; bi < 2; ++bi) ot[ai][bi] = floatx4{0.f, 0.f, 0.f, 0.f};
    float li[2] = {0.f, 0.f};

    for (int t = wave; t < ntiles; t += 4) {
      const int kv0 = t * 64;
      const bool diag = (t == ntiles - 1);

      const ushort_t* kp = kbase + (size_t)(kv0 + ln) * 1024 + quad * 8;
      bf16x8 kf[4][2];
#pragma unroll
      for (int mi = 0; mi < 4; ++mi)
#pragma unroll
        for (int ks = 0; ks < 2; ++ks)
          kf[mi][ks] = ldfrag(kp + mi * 16 * 1024 + ks * 32);

      floatx4 st[4][2];
#pragma unroll
      for (int mi = 0; mi < 4; ++mi)
#pragma unroll
        for (int bi = 0; bi < 2; ++bi) st[mi][bi] = floatx4{0.f, 0.f, 0.f, 0.f};
#pragma unroll
      for (int mi = 0; mi < 4; ++mi)
#pragma unroll
        for (int bi = 0; bi < 2; ++bi) {
          st[mi][bi] = __builtin_amdgcn_mfma_f32_16x16x32_bf16(kf[mi][0], qf[bi][0], st[mi][bi], 0, 0, 0);
          st[mi][bi] = __builtin_amdgcn_mfma_f32_16x16x32_bf16(kf[mi][1], qf[bi][1], st[mi][bi], 0, 0, 0);
        }

      const ushort_t* vp = vbase + (size_t)ln * 2048 + kv0 + quad * 8;
      bf16x8 vf[4][2];
#pragma unroll
      for (int ai = 0; ai < 4; ++ai)
#pragma unroll
        for (int ks = 0; ks < 2; ++ks)
          vf[ai][ks] = ldfrag(vp + ai * 16 * 2048 + ks * 32);

#pragma unroll
      for (int bi = 0; bi < 2; ++bi) {
        const int qrow = qw + bi * 16 + ln;
        float p[4][4];
        if (diag) {
#pragma unroll
          for (int mi = 0; mi < 4; ++mi)
#pragma unroll
            for (int r = 0; r < 4; ++r) {
              const int kv = kv0 + mi * 16 + quad * 4 + r;
              const float e = __builtin_amdgcn_exp2f(st[mi][bi][r]);
              p[mi][r] = (kv > qrow) ? 0.f : e;
            }
        } else {
#pragma unroll
          for (int mi = 0; mi < 4; ++mi)
#pragma unroll
            for (int r = 0; r < 4; ++r) p[mi][r] = __builtin_amdgcn_exp2f(st[mi][bi][r]);
        }
#pragma unroll
        for (int mi = 0; mi < 4; ++mi) {
          li[bi] += (p[mi][0] + p[mi][1]) + (p[mi][2] + p[mi][3]);
          const unsigned d0 = __builtin_amdgcn_perm(
              __builtin_bit_cast(unsigned, p[mi][1]), __builtin_bit_cast(unsigned, p[mi][0]), 0x07060302u);
          const unsigned d1 = __builtin_amdgcn_perm(
              __builtin_bit_cast(unsigned, p[mi][3]), __builtin_bit_cast(unsigned, p[mi][2]), 0x07060302u);
          *(uintx2*)(Pw + (bi * 16 + ln) * 72 + mi * 16 + quad * 4) = uintx2{d0, d1};
        }
      }

      __builtin_amdgcn_fence(__ATOMIC_SEQ_CST, "wavefront");  // compiler ordering only

      bf16x8 pb[2][2];
#pragma unroll
      for (int bi = 0; bi < 2; ++bi)
#pragma unroll
        for (int ks = 0; ks < 2; ++ks)
          pb[bi][ks] = ldfrag(Pw + (bi * 16 + ln) * 72 + ks * 32 + quad * 8);

#pragma unroll
      for (int ai = 0; ai < 4; ++ai)
#pragma unroll
        for (int bi = 0; bi < 2; ++bi) {
          ot[ai][bi] = __builtin_amdgcn_mfma_f32_16x16x32_bf16(vf[ai][0], pb[bi][0], ot[ai][bi], 0, 0, 0);
          ot[ai][bi] = __builtin_amdgcn_mfma_f32_16x16x32_bf16(vf[ai][1], pb[bi][1], ot[ai][bi], 0, 0, 0);
        }
    }

    // --- additive 4-way combine ---
    __syncthreads();  // (B1) all Ps reads done; Cb region (union) safe to write
    if (wave != 0) {
      float* cw = Cb + (wave - 1) * 2176;
#pragma unroll
      for (int bi = 0; bi < 2; ++bi)
#pragma unroll
        for (int ai = 0; ai < 4; ++ai)
          *(floatx4*)&cw[(bi * 16 + ln) * 68 + ai * 16 + quad * 4] = ot[ai][bi];
      lb[(wave - 1) * 128 + lane * 2 + 0] = li[0];
      lb[(wave - 1) * 128 + lane * 2 + 1] = li[1];
    }
    __syncthreads();  // (B2) partials visible
    if (wave == 0) {
#pragma unroll
      for (int w = 0; w < 3; ++w) {
        const float* cw = Cb + w * 2176;
#pragma unroll
        for (int bi = 0; bi < 2; ++bi)
#pragma unroll
          for (int ai = 0; ai < 4; ++ai) {
            const floatx4 o = *(const floatx4*)&cw[(bi * 16 + ln) * 68 + ai * 16 + quad * 4];
#pragma unroll
            for (int r = 0; r < 4; ++r) ot[ai][bi][r] += o[r];
          }
        li[0] += lb[w * 128 + lane * 2 + 0];
        li[1] += lb[w * 128 + lane * 2 + 1];
      }

#pragma unroll
      for (int bi = 0; bi < 2; ++bi) {
        li[bi] += __shfl_xor(li[bi], 16);
        li[bi] += __shfl_xor(li[bi], 32);
        const float inv = 1.0f / li[bi];
        const int qrow = qw + bi * 16 + ln;
        if (f32o) {
          float* of = (float*)out;
#pragma unroll
          for (int ai = 0; ai < 4; ++ai) {
            floatx4 o;
#pragma unroll
            for (int r = 0; r < 4; ++r) o[r] = ot[ai][bi][r] * inv;
            *(floatx4*)(of + (size_t)(b * 2048 + qrow) * 1024 + h * 64 + ai * 16 + quad * 4) = o;
          }
        } else {
          ushort_t* ob = (ushort_t*)out;
#pragma unroll
          for (int ai = 0; ai < 4; ++ai) {
            ushortx4 pk;
#pragma unroll
            for (int r = 0; r < 4; ++r) pk[r] = f2bf(ot[ai][bi][r] * inv);
            *(ushortx4*)(ob + (size_t)(b * 2048 + qrow) * 1024 + h * 64 + ai * 16 + quad * 4) = pk;
          }
        }
      }
    }
    __syncthreads();  // (B3) Cb reads done before next phase reuses Ps space
  }
}

// ---------------------------------------------------------------------------
extern "C" void kernel_launch(void* const* d_in, const int* in_sizes, int n_in,
                              void* d_out, int out_size, void* d_ws, size_t ws_size,
                              hipStream_t stream) {
  char* w = (char*)d_ws;
  int* flag = (int*)w;
  size_t off = 256;
  ushort_t* xb  = (ushort_t*)(w + off); off += (size_t)4194304 * 2;
  ushort_t* wqb = (ushort_t*)(w + off); off += (size_t)1048576 * 2;
  ushort_t* wkb = (ushort_t*)(w + off); off += (size_t)1048576 * 2;
  ushort_t* wvb = (ushort_t*)(w + off); off += (size_t)1048576 * 2;
  float* biasf  = (float*)(w + off);    off += (size_t)3 * 1024 * 4;
  ushort_t* Qw  = (ushort_t*)(w + off); off += (size_t)4194304 * 2;
  ushort_t* Kw  = (ushort_t*)(w + off); off += (size_t)4194304 * 2;
  ushort_t* Vtw = (ushort_t*)(w + off);

  sniff_dtype<<<1, 256, 0, stream>>>((const ushort_t*)d_in[0], flag);
  convert_all<<<dim3(2048, 5), 256, 0, stream>>>(
      d_in[0], d_in[1], d_in[3], d_in[5], d_in[2], d_in[4], d_in[6],
      xb, wqb, wkb, wvb, biasf, flag);
  qkv_gemm<<<dim3(8, 32, 3), 256, 0, stream>>>(xb, wqb, wkb, wvb, biasf, Qw, Kw, Vtw);
  flash4<<<1024, 256, 0, stream>>>(Qw, Kw, Vtw, d_out, flag);
}

// Round 7
// 188.077 us; speedup vs baseline: 1.0373x; 1.0373x over previous
//
#include <hip/hip_runtime.h>

typedef unsigned short ushort_t;
typedef __bf16 bf16x8 __attribute__((ext_vector_type(8)));
typedef unsigned short ushortx8 __attribute__((ext_vector_type(8)));
typedef unsigned short ushortx4 __attribute__((ext_vector_type(4)));
typedef unsigned int uintx2 __attribute__((ext_vector_type(2)));
typedef float floatx4 __attribute__((ext_vector_type(4)));

__device__ inline void load16_lds(const ushort_t* g, ushort_t* l) {
  __builtin_amdgcn_global_load_lds(
      (__attribute__((address_space(1))) void*)(g),
      (__attribute__((address_space(3))) void*)(l),
      16, 0, 0);
}

__device__ inline float bf2f(ushort_t u) {
  unsigned int v = ((unsigned int)u) << 16;
  return __builtin_bit_cast(float, v);
}

__device__ inline ushort_t f2bf(float f) {
  unsigned int u = __builtin_bit_cast(unsigned int, f);
  u += 0x7fffu + ((u >> 16) & 1u);
  return (ushort_t)(u >> 16);
}

__device__ inline bf16x8 ldfrag(const ushort_t* p) {
  return __builtin_bit_cast(bf16x8, *(const ushortx8*)p);
}

// per-wave dtype sniff: sample 64 halfwords of x starting at wave's offset;
// if any decodes (as bf16) to >=1e4 or NaN, inputs are fp32.
// P(wrong | fp32) ~= 0.55^64 ~= 4e-17.
__device__ inline bool sniff_f32(const ushort_t* x, int lane_off) {
  float v = fabsf(bf2f(x[lane_off]));
  bool big = !(v < 1e4f);
  return __ballot(big) != 0ull;
}

// ---------------------------------------------------------------------------
// Canonicalize inputs to bf16 (x, Wq, Wk, Wv) and fp32 biases; inline sniff.
// Block (0, seg=4) publishes the flag for the flash epilogue.
// ---------------------------------------------------------------------------
__global__ __launch_bounds__(256) void convert_all(
    const void* __restrict__ x,
    const void* __restrict__ wq, const void* __restrict__ wk, const void* __restrict__ wv,
    const void* __restrict__ bq, const void* __restrict__ bk, const void* __restrict__ bv,
    ushort_t* __restrict__ xb, ushort_t* __restrict__ wqb,
    ushort_t* __restrict__ wkb, ushort_t* __restrict__ wvb,
    float* __restrict__ biasf, int* __restrict__ flag)
{
  const bool f32 = sniff_f32((const ushort_t*)x, (int)(threadIdx.x & 63));
  const int seg = blockIdx.y;
  if (seg == 4) {
    if (blockIdx.x == 0 && threadIdx.x == 0) *flag = f32 ? 1 : 0;
    const int i = blockIdx.x * 256 + threadIdx.x;
    if (i >= 1024) return;
    const void* bs[3] = {bq, bk, bv};
#pragma unroll
    for (int k = 0; k < 3; ++k)
      biasf[k * 1024 + i] = f32 ? ((const float*)bs[k])[i] : bf2f(((const ushort_t*)bs[k])[i]);
    return;
  }
  const void* src = (seg == 0) ? x : (seg == 1) ? wq : (seg == 2) ? wk : wv;
  ushort_t* dst   = (seg == 0) ? xb : (seg == 1) ? wqb : (seg == 2) ? wkb : wvb;
  const int n = (seg == 0) ? 4194304 : 1048576;
  const int i = (blockIdx.x * 256 + threadIdx.x) * 8;
  if (i >= n) return;
  if (f32) {
    const float* s = (const float*)src + i;
    ushortx8 o;
#pragma unroll
    for (int j = 0; j < 8; ++j) o[j] = f2bf(s[j]);
    *(ushortx8*)(dst + i) = o;
  } else {
    *(ushortx8*)(dst + i) = *(const ushortx8*)((const ushort_t*)src + i);
  }
}

// ---------------------------------------------------------------------------
// QKV projection: out = x @ W^T + b; Q scaled by log2(e)/sqrt(64).
// which==2 (V) writes DIRECTLY in transposed layout Vt(bh,hs,s).
// ---------------------------------------------------------------------------
__global__ __launch_bounds__(256, 2) void qkv_gemm(
    const ushort_t* __restrict__ x,
    const ushort_t* __restrict__ Wq, const ushort_t* __restrict__ Wk,
    const ushort_t* __restrict__ Wv, const float* __restrict__ biasf,
    ushort_t* __restrict__ Qo, ushort_t* __restrict__ Ko, ushort_t* __restrict__ Vt)
{
  __shared__ __attribute__((aligned(16))) ushort_t As[128 * 32];
  __shared__ __attribute__((aligned(16))) ushort_t Bs[128 * 32];

  const int which = blockIdx.z;
  const ushort_t* W = (which == 0) ? Wq : (which == 1) ? Wk : Wv;
  const float oscale = (which == 0) ? 0.18033688011112042f : 1.0f;

  const int n0 = blockIdx.x * 128;
  const int m0 = blockIdx.y * 128;

  const int tid  = threadIdx.x;
  const int wave = tid >> 6;
  const int lane = tid & 63;
  const int ln   = lane & 15;
  const int quad = lane >> 4;
  const int wm = (wave >> 1) * 64;
  const int wn = (wave & 1) * 64;

  floatx4 acc[4][4];
#pragma unroll
  for (int i = 0; i < 4; ++i)
#pragma unroll
    for (int j = 0; j < 4; ++j) acc[i][j] = floatx4{0.f, 0.f, 0.f, 0.f};

  const int c1 = tid, c2 = tid + 256;
  const ushort_t* ga1 = x + (m0 + (c1 >> 2)) * 1024 + (c1 & 3) * 8;
  const ushort_t* ga2 = x + (m0 + (c2 >> 2)) * 1024 + (c2 & 3) * 8;
  const ushort_t* gb1 = W + (n0 + (c1 >> 2)) * 1024 + (c1 & 3) * 8;
  const ushort_t* gb2 = W + (n0 + (c2 >> 2)) * 1024 + (c2 & 3) * 8;
  ushort_t* la1 = As + wave * 512;
  ushort_t* la2 = As + 2048 + wave * 512;
  ushort_t* lb1 = Bs + wave * 512;
  ushort_t* lb2 = Bs + 2048 + wave * 512;

  for (int kt = 0; kt < 1024; kt += 32) {
    __syncthreads();
    load16_lds(ga1 + kt, la1);
    load16_lds(ga2 + kt, la2);
    load16_lds(gb1 + kt, lb1);
    load16_lds(gb2 + kt, lb2);
    __syncthreads();

    bf16x8 af[4], bfr[4];
#pragma unroll
    for (int mi = 0; mi < 4; ++mi)
      af[mi] = ldfrag(As + (wm + mi * 16 + ln) * 32 + quad * 8);
#pragma unroll
    for (int ni = 0; ni < 4; ++ni)
      bfr[ni] = ldfrag(Bs + (wn + ni * 16 + ln) * 32 + quad * 8);
#pragma unroll
    for (int mi = 0; mi < 4; ++mi)
#pragma unroll
      for (int ni = 0; ni < 4; ++ni)
        acc[mi][ni] = __builtin_amdgcn_mfma_f32_16x16x32_bf16(af[mi], bfr[ni], acc[mi][ni], 0, 0, 0);
  }

  float bvv[4];
#pragma unroll
  for (int ni = 0; ni < 4; ++ni) bvv[ni] = biasf[which * 1024 + n0 + wn + ni * 16 + ln];

  if (which == 2) {
#pragma unroll
    for (int mi = 0; mi < 4; ++mi)
#pragma unroll
      for (int ni = 0; ni < 4; ++ni) {
        const int col = n0 + wn + ni * 16 + ln;
        const int row0 = m0 + wm + mi * 16 + quad * 4;
        const int b = row0 >> 11, s0 = row0 & 2047;
        const int h = col >> 6, hs = col & 63;
        ushortx4 pk;
#pragma unroll
        for (int r = 0; r < 4; ++r) pk[r] = f2bf(acc[mi][ni][r] + bvv[ni]);
        *(ushortx4*)(Vt + ((size_t)((b * 16 + h) * 64 + hs)) * 2048 + s0) = pk;
      }
  } else {
    ushort_t* out = (which == 0) ? Qo : Ko;
#pragma unroll
    for (int mi = 0; mi < 4; ++mi)
#pragma unroll
      for (int ni = 0; ni < 4; ++ni) {
        const int col = n0 + wn + ni * 16 + ln;
#pragma unroll
        for (int r = 0; r < 4; ++r) {
          const int row = m0 + wm + mi * 16 + quad * 4 + r;
          out[row * 1024 + col] = f2bf((acc[mi][ni][r] + bvv[ni]) * oscale);
        }
      }
  }
}

// ---------------------------------------------------------------------------
// Flash attention v5 — flash3b structure + ZERO-COST K prefetch.
// kf is dead right after the S^T MFMAs, so the NEXT owned K-tile (t+2) is
// loaded into the SAME kf variable there: the load is in flight across
// softmax + P-LDS round-trip + PV (~600+ cyc), and register pressure is
// unchanged vs flash3b (r4's spill came from the launch_bounds clamp, not
// from prefetching per se). 2-wave blocks, additive combine, 1 barrier.
// ---------------------------------------------------------------------------
__global__ __launch_bounds__(128) void flash5(
    const ushort_t* __restrict__ Q, const ushort_t* __restrict__ Kx,
    const ushort_t* __restrict__ Vt, void* __restrict__ out,
    const int* __restrict__ flag)
{
  __shared__ __attribute__((aligned(16))) ushort_t Ps[2][32 * 72];  // +16B row pad
  __shared__ __attribute__((aligned(16))) float Cb[32][68];
  __shared__ float lbuf[64][2];

  const bool f32o = (*flag != 0);
  const int tid  = threadIdx.x;
  const int wave = tid >> 6;
  const int lane = tid & 63;
  const int ln = lane & 15, quad = lane >> 4;

  // XCD-swizzled, big-chunk-first schedule.
  const int i = blockIdx.x;
  const int xcd = i & 7, j = i >> 3;
  const int bh = xcd * 4 + (j & 3);
  const int c = 63 - (j >> 2);          // q-chunk 0..63, big first
  const int b = bh >> 4, h = bh & 15;
  const int qw = c * 32;
  const int ntiles = (c + 2) >> 1;

  const ushort_t* kbase = Kx + ((size_t)b * 2048) * 1024 + h * 64;
  const ushort_t* vbase = Vt + (size_t)bh * 64 * 2048;

  bf16x8 qf[2][2];
#pragma unroll
  for (int bi = 0; bi < 2; ++bi)
#pragma unroll
    for (int ks = 0; ks < 2; ++ks)
      qf[bi][ks] = ldfrag(Q + (size_t)(b * 2048 + qw + bi * 16 + ln) * 1024 + h * 64 + ks * 32 + quad * 8);

  floatx4 ot[4][2];
#pragma unroll
  for (int ai = 0; ai < 4; ++ai)
#pragma unroll
    for (int bi = 0; bi < 2; ++bi) ot[ai][bi] = floatx4{0.f, 0.f, 0.f, 0.f};
  float li[2] = {0.f, 0.f};

  ushort_t* Pw = Ps[wave];

  // prologue: prefetch first owned K-tile
  bf16x8 kf[4][2];
  if (wave < ntiles) {
    const ushort_t* kp = kbase + (size_t)(wave * 64 + ln) * 1024 + quad * 8;
#pragma unroll
    for (int mi = 0; mi < 4; ++mi)
#pragma unroll
      for (int ks = 0; ks < 2; ++ks)
        kf[mi][ks] = ldfrag(kp + mi * 16 * 1024 + ks * 32);
  }

  for (int t = wave; t < ntiles; t += 2) {
    const int kv0 = t * 64;
    const bool diag = (t == ntiles - 1);

    // V^T A-frags for this tile — issued first, consumed last
    const ushort_t* vp = vbase + (size_t)ln * 2048 + kv0 + quad * 8;
    bf16x8 vf[4][2];
#pragma unroll
    for (int ai = 0; ai < 4; ++ai)
#pragma unroll
      for (int ks = 0; ks < 2; ++ks)
        vf[ai][ks] = ldfrag(vp + ai * 16 * 2048 + ks * 32);

    // S^T = K * Q^T with resident kf
    floatx4 st[4][2];
#pragma unroll
    for (int mi = 0; mi < 4; ++mi)
#pragma unroll
      for (int bi = 0; bi < 2; ++bi) st[mi][bi] = floatx4{0.f, 0.f, 0.f, 0.f};
#pragma unroll
    for (int mi = 0; mi < 4; ++mi)
#pragma unroll
      for (int bi = 0; bi < 2; ++bi) {
        st[mi][bi] = __builtin_amdgcn_mfma_f32_16x16x32_bf16(kf[mi][0], qf[bi][0], st[mi][bi], 0, 0, 0);
        st[mi][bi] = __builtin_amdgcn_mfma_f32_16x16x32_bf16(kf[mi][1], qf[bi][1], st[mi][bi], 0, 0, 0);
      }

    // kf now dead: refill with K(t+2) IN PLACE (clamped; last iter reloads t)
    {
      const int tn = (t + 2 < ntiles) ? (t + 2) : t;
      const ushort_t* kp = kbase + (size_t)(tn * 64 + ln) * 1024 + quad * 8;
#pragma unroll
      for (int mi = 0; mi < 4; ++mi)
#pragma unroll
        for (int ks = 0; ks < 2; ++ks)
          kf[mi][ks] = ldfrag(kp + mi * 16 * 1024 + ks * 32);
    }

    // no-max softmax: p = exp2(s)
#pragma unroll
    for (int bi = 0; bi < 2; ++bi) {
      const int qrow = qw + bi * 16 + ln;
      float p[4][4];
      if (diag) {
#pragma unroll
        for (int mi = 0; mi < 4; ++mi)
#pragma unroll
          for (int r = 0; r < 4; ++r) {
            const int kv = kv0 + mi * 16 + quad * 4 + r;
            const float e = __builtin_amdgcn_exp2f(st[mi][bi][r]);
            p[mi][r] = (kv > qrow) ? 0.f : e;
          }
      } else {
#pragma unroll
        for (int mi = 0; mi < 4; ++mi)
#pragma unroll
          for (int r = 0; r < 4; ++r) p[mi][r] = __builtin_amdgcn_exp2f(st[mi][bi][r]);
      }
#pragma unroll
      for (int mi = 0; mi < 4; ++mi) {
        li[bi] += (p[mi][0] + p[mi][1]) + (p[mi][2] + p[mi][3]);
        const unsigned d0 = __builtin_amdgcn_perm(
            __builtin_bit_cast(unsigned, p[mi][1]), __builtin_bit_cast(unsigned, p[mi][0]), 0x07060302u);
        const unsigned d1 = __builtin_amdgcn_perm(
            __builtin_bit_cast(unsigned, p[mi][3]), __builtin_bit_cast(unsigned, p[mi][2]), 0x07060302u);
        *(uintx2*)(Pw + (bi * 16 + ln) * 72 + mi * 16 + quad * 4) = uintx2{d0, d1};
      }
    }

    __builtin_amdgcn_fence(__ATOMIC_SEQ_CST, "wavefront");  // compiler ordering only

    bf16x8 pb[2][2];
#pragma unroll
    for (int bi = 0; bi < 2; ++bi)
#pragma unroll
      for (int ks = 0; ks < 2; ++ks)
        pb[bi][ks] = ldfrag(Pw + (bi * 16 + ln) * 72 + ks * 32 + quad * 8);

#pragma unroll
    for (int ai = 0; ai < 4; ++ai)
#pragma unroll
      for (int bi = 0; bi < 2; ++bi) {
        ot[ai][bi] = __builtin_amdgcn_mfma_f32_16x16x32_bf16(vf[ai][0], pb[bi][0], ot[ai][bi], 0, 0, 0);
        ot[ai][bi] = __builtin_amdgcn_mfma_f32_16x16x32_bf16(vf[ai][1], pb[bi][1], ot[ai][bi], 0, 0, 0);
      }
  }

  // cross-wave combine (no-max softmax partials are additive)
  if (wave == 1) {
#pragma unroll
    for (int bi = 0; bi < 2; ++bi)
#pragma unroll
      for (int ai = 0; ai < 4; ++ai)
        *(floatx4*)&Cb[bi * 16 + ln][ai * 16 + quad * 4] = ot[ai][bi];
    lbuf[lane][0] = li[0];
    lbuf[lane][1] = li[1];
  }
  __syncthreads();
  if (wave == 0) {
#pragma unroll
    for (int bi = 0; bi < 2; ++bi)
#pragma unroll
      for (int ai = 0; ai < 4; ++ai) {
        const floatx4 o = *(const floatx4*)&Cb[bi * 16 + ln][ai * 16 + quad * 4];
#pragma unroll
        for (int r = 0; r < 4; ++r) ot[ai][bi][r] += o[r];
      }
    li[0] += lbuf[lane][0];
    li[1] += lbuf[lane][1];

#pragma unroll
    for (int bi = 0; bi < 2; ++bi) {
      li[bi] += __shfl_xor(li[bi], 16);
      li[bi] += __shfl_xor(li[bi], 32);
      const float inv = 1.0f / li[bi];
      const int qrow = qw + bi * 16 + ln;
      if (f32o) {
        float* of = (float*)out;
#pragma unroll
        for (int ai = 0; ai < 4; ++ai) {
          floatx4 o;
#pragma unroll
          for (int r = 0; r < 4; ++r) o[r] = ot[ai][bi][r] * inv;
          *(floatx4*)(of + (size_t)(b * 2048 + qrow) * 1024 + h * 64 + ai * 16 + quad * 4) = o;
        }
      } else {
        ushort_t* ob = (ushort_t*)out;
#pragma unroll
        for (int ai = 0; ai < 4; ++ai) {
          ushortx4 pk;
#pragma unroll
          for (int r = 0; r < 4; ++r) pk[r] = f2bf(ot[ai][bi][r] * inv);
          *(ushortx4*)(ob + (size_t)(b * 2048 + qrow) * 1024 + h * 64 + ai * 16 + quad * 4) = pk;
        }
      }
    }
  }
}

// ---------------------------------------------------------------------------
extern "C" void kernel_launch(void* const* d_in, const int* in_sizes, int n_in,
                              void* d_out, int out_size, void* d_ws, size_t ws_size,
                              hipStream_t stream) {
  char* w = (char*)d_ws;
  int* flag = (int*)w;
  size_t off = 256;
  ushort_t* xb  = (ushort_t*)(w + off); off += (size_t)4194304 * 2;
  ushort_t* wqb = (ushort_t*)(w + off); off += (size_t)1048576 * 2;
  ushort_t* wkb = (ushort_t*)(w + off); off += (size_t)1048576 * 2;
  ushort_t* wvb = (ushort_t*)(w + off); off += (size_t)1048576 * 2;
  float* biasf  = (float*)(w + off);    off += (size_t)3 * 1024 * 4;
  ushort_t* Qw  = (ushort_t*)(w + off); off += (size_t)4194304 * 2;
  ushort_t* Kw  = (ushort_t*)(w + off); off += (size_t)4194304 * 2;
  ushort_t* Vtw = (ushort_t*)(w + off);

  convert_all<<<dim3(2048, 5), 256, 0, stream>>>(
      d_in[0], d_in[1], d_in[3], d_in[5], d_in[2], d_in[4], d_in[6],
      xb, wqb, wkb, wvb, biasf, flag);
  qkv_gemm<<<dim3(8, 32, 3), 256, 0, stream>>>(xb, wqb, wkb, wvb, biasf, Qw, Kw, Vtw);
  flash5<<<2048, 128, 0, stream>>>(Qw, Kw, Vtw, d_out, flag);
}

// Round 8
// 186.601 us; speedup vs baseline: 1.0455x; 1.0079x over previous
//
#include <hip/hip_runtime.h>

typedef unsigned short ushort_t;
typedef __bf16 bf16x8 __attribute__((ext_vector_type(8)));
typedef unsigned short ushortx8 __attribute__((ext_vector_type(8)));
typedef unsigned short ushortx4 __attribute__((ext_vector_type(4)));
typedef unsigned int uintx4 __attribute__((ext_vector_type(4)));
typedef float floatx4 __attribute__((ext_vector_type(4)));

__device__ inline void load16_lds(const ushort_t* g, ushort_t* l) {
  __builtin_amdgcn_global_load_lds(
      (__attribute__((address_space(1))) void*)(g),
      (__attribute__((address_space(3))) void*)(l),
      16, 0, 0);
}

__device__ inline float bf2f(ushort_t u) {
  unsigned int v = ((unsigned int)u) << 16;
  return __builtin_bit_cast(float, v);
}

__device__ inline ushort_t f2bf(float f) {
  unsigned int u = __builtin_bit_cast(unsigned int, f);
  u += 0x7fffu + ((u >> 16) & 1u);
  return (ushort_t)(u >> 16);
}

__device__ inline bf16x8 ldfrag(const ushort_t* p) {
  return __builtin_bit_cast(bf16x8, *(const ushortx8*)p);
}

// per-wave dtype sniff; P(wrong | fp32) ~= 0.55^64 ~= 4e-17.
__device__ inline bool sniff_f32(const ushort_t* x, int lane_off) {
  float v = fabsf(bf2f(x[lane_off]));
  bool big = !(v < 1e4f);
  return __ballot(big) != 0ull;
}

// ---------------------------------------------------------------------------
// Canonicalize inputs to bf16 (x, Wq, Wk, Wv) and fp32 biases; inline sniff.
// ---------------------------------------------------------------------------
__global__ __launch_bounds__(256) void convert_all(
    const void* __restrict__ x,
    const void* __restrict__ wq, const void* __restrict__ wk, const void* __restrict__ wv,
    const void* __restrict__ bq, const void* __restrict__ bk, const void* __restrict__ bv,
    ushort_t* __restrict__ xb, ushort_t* __restrict__ wqb,
    ushort_t* __restrict__ wkb, ushort_t* __restrict__ wvb,
    float* __restrict__ biasf, int* __restrict__ flag)
{
  const bool f32 = sniff_f32((const ushort_t*)x, (int)(threadIdx.x & 63));
  const int seg = blockIdx.y;
  if (seg == 4) {
    if (blockIdx.x == 0 && threadIdx.x == 0) *flag = f32 ? 1 : 0;
    const int i = blockIdx.x * 256 + threadIdx.x;
    if (i >= 1024) return;
    const void* bs[3] = {bq, bk, bv};
#pragma unroll
    for (int k = 0; k < 3; ++k)
      biasf[k * 1024 + i] = f32 ? ((const float*)bs[k])[i] : bf2f(((const ushort_t*)bs[k])[i]);
    return;
  }
  const void* src = (seg == 0) ? x : (seg == 1) ? wq : (seg == 2) ? wk : wv;
  ushort_t* dst   = (seg == 0) ? xb : (seg == 1) ? wqb : (seg == 2) ? wkb : wvb;
  const int n = (seg == 0) ? 4194304 : 1048576;
  const int i = (blockIdx.x * 256 + threadIdx.x) * 8;
  if (i >= n) return;
  if (f32) {
    const float* s = (const float*)src + i;
    ushortx8 o;
#pragma unroll
    for (int j = 0; j < 8; ++j) o[j] = f2bf(s[j]);
    *(ushortx8*)(dst + i) = o;
  } else {
    *(ushortx8*)(dst + i) = *(const ushortx8*)((const ushort_t*)src + i);
  }
}

// ---------------------------------------------------------------------------
// QKV projection: out = x @ W^T + b; Q scaled by log2(e)/sqrt(64).
// which==2 (V) writes DIRECTLY in transposed layout Vt(bh,hs,s).
// ---------------------------------------------------------------------------
__global__ __launch_bounds__(256, 2) void qkv_gemm(
    const ushort_t* __restrict__ x,
    const ushort_t* __restrict__ Wq, const ushort_t* __restrict__ Wk,
    const ushort_t* __restrict__ Wv, const float* __restrict__ biasf,
    ushort_t* __restrict__ Qo, ushort_t* __restrict__ Ko, ushort_t* __restrict__ Vt)
{
  __shared__ __attribute__((aligned(16))) ushort_t As[128 * 32];
  __shared__ __attribute__((aligned(16))) ushort_t Bs[128 * 32];

  const int which = blockIdx.z;
  const ushort_t* W = (which == 0) ? Wq : (which == 1) ? Wk : Wv;
  const float oscale = (which == 0) ? 0.18033688011112042f : 1.0f;

  const int n0 = blockIdx.x * 128;
  const int m0 = blockIdx.y * 128;

  const int tid  = threadIdx.x;
  const int wave = tid >> 6;
  const int lane = tid & 63;
  const int ln   = lane & 15;
  const int quad = lane >> 4;
  const int wm = (wave >> 1) * 64;
  const int wn = (wave & 1) * 64;

  floatx4 acc[4][4];
#pragma unroll
  for (int i = 0; i < 4; ++i)
#pragma unroll
    for (int j = 0; j < 4; ++j) acc[i][j] = floatx4{0.f, 0.f, 0.f, 0.f};

  const int c1 = tid, c2 = tid + 256;
  const ushort_t* ga1 = x + (m0 + (c1 >> 2)) * 1024 + (c1 & 3) * 8;
  const ushort_t* ga2 = x + (m0 + (c2 >> 2)) * 1024 + (c2 & 3) * 8;
  const ushort_t* gb1 = W + (n0 + (c1 >> 2)) * 1024 + (c1 & 3) * 8;
  const ushort_t* gb2 = W + (n0 + (c2 >> 2)) * 1024 + (c2 & 3) * 8;
  ushort_t* la1 = As + wave * 512;
  ushort_t* la2 = As + 2048 + wave * 512;
  ushort_t* lb1 = Bs + wave * 512;
  ushort_t* lb2 = Bs + 2048 + wave * 512;

  for (int kt = 0; kt < 1024; kt += 32) {
    __syncthreads();
    load16_lds(ga1 + kt, la1);
    load16_lds(ga2 + kt, la2);
    load16_lds(gb1 + kt, lb1);
    load16_lds(gb2 + kt, lb2);
    __syncthreads();

    bf16x8 af[4], bfr[4];
#pragma unroll
    for (int mi = 0; mi < 4; ++mi)
      af[mi] = ldfrag(As + (wm + mi * 16 + ln) * 32 + quad * 8);
#pragma unroll
    for (int ni = 0; ni < 4; ++ni)
      bfr[ni] = ldfrag(Bs + (wn + ni * 16 + ln) * 32 + quad * 8);
#pragma unroll
    for (int mi = 0; mi < 4; ++mi)
#pragma unroll
      for (int ni = 0; ni < 4; ++ni)
        acc[mi][ni] = __builtin_amdgcn_mfma_f32_16x16x32_bf16(af[mi], bfr[ni], acc[mi][ni], 0, 0, 0);
  }

  float bvv[4];
#pragma unroll
  for (int ni = 0; ni < 4; ++ni) bvv[ni] = biasf[which * 1024 + n0 + wn + ni * 16 + ln];

  if (which == 2) {
#pragma unroll
    for (int mi = 0; mi < 4; ++mi)
#pragma unroll
      for (int ni = 0; ni < 4; ++ni) {
        const int col = n0 + wn + ni * 16 + ln;
        const int row0 = m0 + wm + mi * 16 + quad * 4;
        const int b = row0 >> 11, s0 = row0 & 2047;
        const int h = col >> 6, hs = col & 63;
        ushortx4 pk;
#pragma unroll
        for (int r = 0; r < 4; ++r) pk[r] = f2bf(acc[mi][ni][r] + bvv[ni]);
        *(ushortx4*)(Vt + ((size_t)((b * 16 + h) * 64 + hs)) * 2048 + s0) = pk;
      }
  } else {
    ushort_t* out = (which == 0) ? Qo : Ko;
#pragma unroll
    for (int mi = 0; mi < 4; ++mi)
#pragma unroll
      for (int ni = 0; ni < 4; ++ni) {
        const int col = n0 + wn + ni * 16 + ln;
#pragma unroll
        for (int r = 0; r < 4; ++r) {
          const int row = m0 + wm + mi * 16 + quad * 4 + r;
          out[row * 1024 + col] = f2bf((acc[mi][ni][r] + bvv[ni]) * oscale);
        }
      }
  }
}

// ---------------------------------------------------------------------------
// Flash attention v6 — P transform via ds_bpermute: NO LDS round-trip, NO
// fence, NO bank conflicts in the loop. The C->A layout change is a pure
// quad-permutation at fixed ln:
//   pb[ks].dword[j] comes from lane ln + 16*((quad&1)*2 + (j>>1)),
//   register d[2ks + (quad>>1)][j&1]
// (2 bpermutes + 1 cndmask per dword; the (quad>>1) register choice is
// resolved by dual bpermute + select). K-tile prefetch (in-place refill)
// can now genuinely stay in flight across the softmax.
// 2-wave blocks, additive no-max softmax combine, 1 barrier at the end.
// ---------------------------------------------------------------------------
__global__ __launch_bounds__(128) void flash6(
    const ushort_t* __restrict__ Q, const ushort_t* __restrict__ Kx,
    const ushort_t* __restrict__ Vt, void* __restrict__ out,
    const int* __restrict__ flag)
{
  __shared__ __attribute__((aligned(16))) float Cb[32][68];
  __shared__ float lbuf[64][2];

  const bool f32o = (*flag != 0);
  const int tid  = threadIdx.x;
  const int wave = tid >> 6;
  const int lane = tid & 63;
  const int ln = lane & 15, quad = lane >> 4;

  // bpermute indices (bytes): idxA for j=0,1; idxB for j=2,3
  const int idxA = (ln + 32 * (quad & 1)) * 4;
  const int idxB = idxA + 64;
  const bool hiq = (quad >> 1) != 0;

  // XCD-swizzled, big-chunk-first schedule.
  const int i = blockIdx.x;
  const int xcd = i & 7, j = i >> 3;
  const int bh = xcd * 4 + (j & 3);
  const int c = 63 - (j >> 2);          // q-chunk 0..63, big first
  const int b = bh >> 4, h = bh & 15;
  const int qw = c * 32;
  const int ntiles = (c + 2) >> 1;

  const ushort_t* kbase = Kx + ((size_t)b * 2048) * 1024 + h * 64;
  const ushort_t* vbase = Vt + (size_t)bh * 64 * 2048;

  bf16x8 qf[2][2];
#pragma unroll
  for (int bi = 0; bi < 2; ++bi)
#pragma unroll
    for (int ks = 0; ks < 2; ++ks)
      qf[bi][ks] = ldfrag(Q + (size_t)(b * 2048 + qw + bi * 16 + ln) * 1024 + h * 64 + ks * 32 + quad * 8);

  floatx4 ot[4][2];
#pragma unroll
  for (int ai = 0; ai < 4; ++ai)
#pragma unroll
    for (int bi = 0; bi < 2; ++bi) ot[ai][bi] = floatx4{0.f, 0.f, 0.f, 0.f};
  float li[2] = {0.f, 0.f};

  // prologue: prefetch first owned K-tile
  bf16x8 kf[4][2];
  if (wave < ntiles) {
    const ushort_t* kp = kbase + (size_t)(wave * 64 + ln) * 1024 + quad * 8;
#pragma unroll
    for (int mi = 0; mi < 4; ++mi)
#pragma unroll
      for (int ks = 0; ks < 2; ++ks)
        kf[mi][ks] = ldfrag(kp + mi * 16 * 1024 + ks * 32);
  }

  for (int t = wave; t < ntiles; t += 2) {
    const int kv0 = t * 64;
    const bool diag = (t == ntiles - 1);

    // V^T A-frags for this tile — issued first, consumed last
    const ushort_t* vp = vbase + (size_t)ln * 2048 + kv0 + quad * 8;
    bf16x8 vf[4][2];
#pragma unroll
    for (int ai = 0; ai < 4; ++ai)
#pragma unroll
      for (int ks = 0; ks < 2; ++ks)
        vf[ai][ks] = ldfrag(vp + ai * 16 * 2048 + ks * 32);

    // S^T = K * Q^T with resident kf
    floatx4 st[4][2];
#pragma unroll
    for (int mi = 0; mi < 4; ++mi)
#pragma unroll
      for (int bi = 0; bi < 2; ++bi) st[mi][bi] = floatx4{0.f, 0.f, 0.f, 0.f};
#pragma unroll
    for (int mi = 0; mi < 4; ++mi)
#pragma unroll
      for (int bi = 0; bi < 2; ++bi) {
        st[mi][bi] = __builtin_amdgcn_mfma_f32_16x16x32_bf16(kf[mi][0], qf[bi][0], st[mi][bi], 0, 0, 0);
        st[mi][bi] = __builtin_amdgcn_mfma_f32_16x16x32_bf16(kf[mi][1], qf[bi][1], st[mi][bi], 0, 0, 0);
      }

    // kf dead: refill with K(t+2) in place (clamped; stays in flight now)
    {
      const int tn = (t + 2 < ntiles) ? (t + 2) : t;
      const ushort_t* kp = kbase + (size_t)(tn * 64 + ln) * 1024 + quad * 8;
#pragma unroll
      for (int mi = 0; mi < 4; ++mi)
#pragma unroll
        for (int ks = 0; ks < 2; ++ks)
          kf[mi][ks] = ldfrag(kp + mi * 16 * 1024 + ks * 32);
    }

    // no-max softmax + in-register C->A transform
    bf16x8 pb[2][2];
#pragma unroll
    for (int bi = 0; bi < 2; ++bi) {
      const int qrow = qw + bi * 16 + ln;
      float p[4][4];
      if (diag) {
#pragma unroll
        for (int mi = 0; mi < 4; ++mi)
#pragma unroll
          for (int r = 0; r < 4; ++r) {
            const int kv = kv0 + mi * 16 + quad * 4 + r;
            const float e = __builtin_amdgcn_exp2f(st[mi][bi][r]);
            p[mi][r] = (kv > qrow) ? 0.f : e;
          }
      } else {
#pragma unroll
        for (int mi = 0; mi < 4; ++mi)
#pragma unroll
          for (int r = 0; r < 4; ++r) p[mi][r] = __builtin_amdgcn_exp2f(st[mi][bi][r]);
      }
      unsigned d[4][2];
#pragma unroll
      for (int mi = 0; mi < 4; ++mi) {
        li[bi] += (p[mi][0] + p[mi][1]) + (p[mi][2] + p[mi][3]);
        d[mi][0] = __builtin_amdgcn_perm(
            __builtin_bit_cast(unsigned, p[mi][1]), __builtin_bit_cast(unsigned, p[mi][0]), 0x07060302u);
        d[mi][1] = __builtin_amdgcn_perm(
            __builtin_bit_cast(unsigned, p[mi][3]), __builtin_bit_cast(unsigned, p[mi][2]), 0x07060302u);
      }
#pragma unroll
      for (int ks = 0; ks < 2; ++ks) {
        uintx4 w;
#pragma unroll
        for (int jj = 0; jj < 4; ++jj) {
          const int idx = (jj >> 1) ? idxB : idxA;
          const int lo = __builtin_amdgcn_ds_bpermute(idx, (int)d[2 * ks][jj & 1]);
          const int hi = __builtin_amdgcn_ds_bpermute(idx, (int)d[2 * ks + 1][jj & 1]);
          w[jj] = (unsigned)(hiq ? hi : lo);
        }
        pb[bi][ks] = __builtin_bit_cast(bf16x8, w);
      }
    }

#pragma unroll
    for (int ai = 0; ai < 4; ++ai)
#pragma unroll
      for (int bi = 0; bi < 2; ++bi) {
        ot[ai][bi] = __builtin_amdgcn_mfma_f32_16x16x32_bf16(vf[ai][0], pb[bi][0], ot[ai][bi], 0, 0, 0);
        ot[ai][bi] = __builtin_amdgcn_mfma_f32_16x16x32_bf16(vf[ai][1], pb[bi][1], ot[ai][bi], 0, 0, 0);
      }
  }

  // cross-wave combine (no-max softmax partials are additive)
  if (wave == 1) {
#pragma unroll
    for (int bi = 0; bi < 2; ++bi)
#pragma unroll
      for (int ai = 0; ai < 4; ++ai)
        *(floatx4*)&Cb[bi * 16 + ln][ai * 16 + quad * 4] = ot[ai][bi];
    lbuf[lane][0] = li[0];
    lbuf[lane][1] = li[1];
  }
  __syncthreads();
  if (wave == 0) {
#pragma unroll
    for (int bi = 0; bi < 2; ++bi)
#pragma unroll
      for (int ai = 0; ai < 4; ++ai) {
        const floatx4 o = *(const floatx4*)&Cb[bi * 16 + ln][ai * 16 + quad * 4];
#pragma unroll
        for (int r = 0; r < 4; ++r) ot[ai][bi][r] += o[r];
      }
    li[0] += lbuf[lane][0];
    li[1] += lbuf[lane][1];

#pragma unroll
    for (int bi = 0; bi < 2; ++bi) {
      li[bi] += __shfl_xor(li[bi], 16);
      li[bi] += __shfl_xor(li[bi], 32);
      const float inv = 1.0f / li[bi];
      const int qrow = qw + bi * 16 + ln;
      if (f32o) {
        float* of = (float*)out;
#pragma unroll
        for (int ai = 0; ai < 4; ++ai) {
          floatx4 o;
#pragma unroll
          for (int r = 0; r < 4; ++r) o[r] = ot[ai][bi][r] * inv;
          *(floatx4*)(of + (size_t)(b * 2048 + qrow) * 1024 + h * 64 + ai * 16 + quad * 4) = o;
        }
      } else {
        ushort_t* ob = (ushort_t*)out;
#pragma unroll
        for (int ai = 0; ai < 4; ++ai) {
          ushortx4 pk;
#pragma unroll
          for (int r = 0; r < 4; ++r) pk[r] = f2bf(ot[ai][bi][r] * inv);
          *(ushortx4*)(ob + (size_t)(b * 2048 + qrow) * 1024 + h * 64 + ai * 16 + quad * 4) = pk;
        }
      }
    }
  }
}

// ---------------------------------------------------------------------------
extern "C" void kernel_launch(void* const* d_in, const int* in_sizes, int n_in,
                              void* d_out, int out_size, void* d_ws, size_t ws_size,
                              hipStream_t stream) {
  char* w = (char*)d_ws;
  int* flag = (int*)w;
  size_t off = 256;
  ushort_t* xb  = (ushort_t*)(w + off); off += (size_t)4194304 * 2;
  ushort_t* wqb = (ushort_t*)(w + off); off += (size_t)1048576 * 2;
  ushort_t* wkb = (ushort_t*)(w + off); off += (size_t)1048576 * 2;
  ushort_t* wvb = (ushort_t*)(w + off); off += (size_t)1048576 * 2;
  float* biasf  = (float*)(w + off);    off += (size_t)3 * 1024 * 4;
  ushort_t* Qw  = (ushort_t*)(w + off); off += (size_t)4194304 * 2;
  ushort_t* Kw  = (ushort_t*)(w + off); off += (size_t)4194304 * 2;
  ushort_t* Vtw = (ushort_t*)(w + off);

  convert_all<<<dim3(2048, 5), 256, 0, stream>>>(
      d_in[0], d_in[1], d_in[3], d_in[5], d_in[2], d_in[4], d_in[6],
      xb, wqb, wkb, wvb, biasf, flag);
  qkv_gemm<<<dim3(8, 32, 3), 256, 0, stream>>>(xb, wqb, wkb, wvb, biasf, Qw, Kw, Vtw);
  flash6<<<2048, 128, 0, stream>>>(Qw, Kw, Vtw, d_out, flag);
}

// Round 9
// 161.316 us; speedup vs baseline: 1.2094x; 1.1567x over previous
//
#include <hip/hip_runtime.h>

typedef unsigned short ushort_t;
typedef __bf16 bf16x8 __attribute__((ext_vector_type(8)));
typedef unsigned short ushortx8 __attribute__((ext_vector_type(8)));
typedef unsigned short ushortx4 __attribute__((ext_vector_type(4)));
typedef unsigned int uintx4 __attribute__((ext_vector_type(4)));
typedef float floatx4 __attribute__((ext_vector_type(4)));

__device__ inline void load16_lds(const ushort_t* g, ushort_t* l) {
  __builtin_amdgcn_global_load_lds(
      (__attribute__((address_space(1))) void*)(g),
      (__attribute__((address_space(3))) void*)(l),
      16, 0, 0);
}

__device__ inline float bf2f(ushort_t u) {
  unsigned int v = ((unsigned int)u) << 16;
  return __builtin_bit_cast(float, v);
}

__device__ inline ushort_t f2bf(float f) {
  unsigned int u = __builtin_bit_cast(unsigned int, f);
  u += 0x7fffu + ((u >> 16) & 1u);
  return (ushort_t)(u >> 16);
}

__device__ inline bf16x8 ldfrag(const ushort_t* p) {
  return __builtin_bit_cast(bf16x8, *(const ushortx8*)p);
}

// per-wave dtype sniff; P(wrong | fp32) ~= 0.55^64 ~= 4e-17.
__device__ inline bool sniff_f32(const ushort_t* x, int lane_off) {
  float v = fabsf(bf2f(x[lane_off]));
  bool big = !(v < 1e4f);
  return __ballot(big) != 0ull;
}

// ---------------------------------------------------------------------------
// Canonicalize inputs to bf16 (x, Wq, Wk, Wv) and fp32 biases; inline sniff.
// ---------------------------------------------------------------------------
__global__ __launch_bounds__(256) void convert_all(
    const void* __restrict__ x,
    const void* __restrict__ wq, const void* __restrict__ wk, const void* __restrict__ wv,
    const void* __restrict__ bq, const void* __restrict__ bk, const void* __restrict__ bv,
    ushort_t* __restrict__ xb, ushort_t* __restrict__ wqb,
    ushort_t* __restrict__ wkb, ushort_t* __restrict__ wvb,
    float* __restrict__ biasf, int* __restrict__ flag)
{
  const bool f32 = sniff_f32((const ushort_t*)x, (int)(threadIdx.x & 63));
  const int seg = blockIdx.y;
  if (seg == 4) {
    if (blockIdx.x == 0 && threadIdx.x == 0) *flag = f32 ? 1 : 0;
    const int i = blockIdx.x * 256 + threadIdx.x;
    if (i >= 1024) return;
    const void* bs[3] = {bq, bk, bv};
#pragma unroll
    for (int k = 0; k < 3; ++k)
      biasf[k * 1024 + i] = f32 ? ((const float*)bs[k])[i] : bf2f(((const ushort_t*)bs[k])[i]);
    return;
  }
  const void* src = (seg == 0) ? x : (seg == 1) ? wq : (seg == 2) ? wk : wv;
  ushort_t* dst   = (seg == 0) ? xb : (seg == 1) ? wqb : (seg == 2) ? wkb : wvb;
  const int n = (seg == 0) ? 4194304 : 1048576;
  const int i = (blockIdx.x * 256 + threadIdx.x) * 8;
  if (i >= n) return;
  if (f32) {
    const float* s = (const float*)src + i;
    ushortx8 o;
#pragma unroll
    for (int j = 0; j < 8; ++j) o[j] = f2bf(s[j]);
    *(ushortx8*)(dst + i) = o;
  } else {
    *(ushortx8*)(dst + i) = *(const ushortx8*)((const ushort_t*)src + i);
  }
}

// ---------------------------------------------------------------------------
// QKV projection: out = x @ W^T + b; Q scaled by log2(e)/sqrt(64).
// which==2 (V) writes DIRECTLY in transposed layout Vt(bh,hs,s).
// ---------------------------------------------------------------------------
__global__ __launch_bounds__(256, 2) void qkv_gemm(
    const ushort_t* __restrict__ x,
    const ushort_t* __restrict__ Wq, const ushort_t* __restrict__ Wk,
    const ushort_t* __restrict__ Wv, const float* __restrict__ biasf,
    ushort_t* __restrict__ Qo, ushort_t* __restrict__ Ko, ushort_t* __restrict__ Vt)
{
  __shared__ __attribute__((aligned(16))) ushort_t As[128 * 32];
  __shared__ __attribute__((aligned(16))) ushort_t Bs[128 * 32];

  const int which = blockIdx.z;
  const ushort_t* W = (which == 0) ? Wq : (which == 1) ? Wk : Wv;
  const float oscale = (which == 0) ? 0.18033688011112042f : 1.0f;

  const int n0 = blockIdx.x * 128;
  const int m0 = blockIdx.y * 128;

  const int tid  = threadIdx.x;
  const int wave = tid >> 6;
  const int lane = tid & 63;
  const int ln   = lane & 15;
  const int quad = lane >> 4;
  const int wm = (wave >> 1) * 64;
  const int wn = (wave & 1) * 64;

  floatx4 acc[4][4];
#pragma unroll
  for (int i = 0; i < 4; ++i)
#pragma unroll
    for (int j = 0; j < 4; ++j) acc[i][j] = floatx4{0.f, 0.f, 0.f, 0.f};

  const int c1 = tid, c2 = tid + 256;
  const ushort_t* ga1 = x + (m0 + (c1 >> 2)) * 1024 + (c1 & 3) * 8;
  const ushort_t* ga2 = x + (m0 + (c2 >> 2)) * 1024 + (c2 & 3) * 8;
  const ushort_t* gb1 = W + (n0 + (c1 >> 2)) * 1024 + (c1 & 3) * 8;
  const ushort_t* gb2 = W + (n0 + (c2 >> 2)) * 1024 + (c2 & 3) * 8;
  ushort_t* la1 = As + wave * 512;
  ushort_t* la2 = As + 2048 + wave * 512;
  ushort_t* lb1 = Bs + wave * 512;
  ushort_t* lb2 = Bs + 2048 + wave * 512;

  for (int kt = 0; kt < 1024; kt += 32) {
    __syncthreads();
    load16_lds(ga1 + kt, la1);
    load16_lds(ga2 + kt, la2);
    load16_lds(gb1 + kt, lb1);
    load16_lds(gb2 + kt, lb2);
    __syncthreads();

    bf16x8 af[4], bfr[4];
#pragma unroll
    for (int mi = 0; mi < 4; ++mi)
      af[mi] = ldfrag(As + (wm + mi * 16 + ln) * 32 + quad * 8);
#pragma unroll
    for (int ni = 0; ni < 4; ++ni)
      bfr[ni] = ldfrag(Bs + (wn + ni * 16 + ln) * 32 + quad * 8);
#pragma unroll
    for (int mi = 0; mi < 4; ++mi)
#pragma unroll
      for (int ni = 0; ni < 4; ++ni)
        acc[mi][ni] = __builtin_amdgcn_mfma_f32_16x16x32_bf16(af[mi], bfr[ni], acc[mi][ni], 0, 0, 0);
  }

  float bvv[4];
#pragma unroll
  for (int ni = 0; ni < 4; ++ni) bvv[ni] = biasf[which * 1024 + n0 + wn + ni * 16 + ln];

  if (which == 2) {
#pragma unroll
    for (int mi = 0; mi < 4; ++mi)
#pragma unroll
      for (int ni = 0; ni < 4; ++ni) {
        const int col = n0 + wn + ni * 16 + ln;
        const int row0 = m0 + wm + mi * 16 + quad * 4;
        const int b = row0 >> 11, s0 = row0 & 2047;
        const int h = col >> 6, hs = col & 63;
        ushortx4 pk;
#pragma unroll
        for (int r = 0; r < 4; ++r) pk[r] = f2bf(acc[mi][ni][r] + bvv[ni]);
        *(ushortx4*)(Vt + ((size_t)((b * 16 + h) * 64 + hs)) * 2048 + s0) = pk;
      }
  } else {
    ushort_t* out = (which == 0) ? Qo : Ko;
#pragma unroll
    for (int mi = 0; mi < 4; ++mi)
#pragma unroll
      for (int ni = 0; ni < 4; ++ni) {
        const int col = n0 + wn + ni * 16 + ln;
#pragma unroll
        for (int r = 0; r < 4; ++r) {
          const int row = m0 + wm + mi * 16 + quad * 4 + r;
          out[row * 1024 + col] = f2bf((acc[mi][ni][r] + bvv[ni]) * oscale);
        }
      }
  }
}

// ---------------------------------------------------------------------------
// Flash attention v8 — DOUBLED work quantum: q=64 rows per wave, kv=64/tile.
// Halves wave-tile count (33.8k -> 16.9k) and halves K/V L2 traffic; per tile
// 64 MFMA + 16 global loads. Inner loop restructured per-bi (S -> softmax ->
// bpermute -> PV) to keep st/pb live ranges tiny (~220 VGPR peak, no clamp).
// Block = 128 thr (2 waves), both waves own the SAME 64 q-rows, kv tiles
// split even/odd; additive no-max combine at the end (1 barrier).
// ---------------------------------------------------------------------------
__global__ __launch_bounds__(128) void flash8(
    const ushort_t* __restrict__ Q, const ushort_t* __restrict__ Kx,
    const ushort_t* __restrict__ Vt, void* __restrict__ out,
    const int* __restrict__ flag)
{
  __shared__ __attribute__((aligned(16))) float Cb[64][68];
  __shared__ float lbuf[64][4];

  const bool f32o = (*flag != 0);
  const int tid  = threadIdx.x;
  const int wave = tid >> 6;
  const int lane = tid & 63;
  const int ln = lane & 15, quad = lane >> 4;

  // bpermute indices (bytes): idxA for j=0,1; idxB for j=2,3
  const int idxA = (ln + 32 * (quad & 1)) * 4;
  const int idxB = idxA + 64;
  const bool hiq = (quad >> 1) != 0;

  // XCD-swizzled, big-chunk-first: 1024 blocks = 32 bh x 32 chunks of 64 rows.
  const int i = blockIdx.x;
  const int xcd = i & 7, j = i >> 3;
  const int bh = xcd * 4 + (j & 3);
  const int cc = 31 - (j >> 2);         // q-chunk 0..31, big first
  const int b = bh >> 4, h = bh & 15;
  const int qw = cc * 64;
  const int ntiles = cc + 1;

  const ushort_t* kbase = Kx + ((size_t)b * 2048) * 1024 + h * 64;
  const ushort_t* vbase = Vt + (size_t)bh * 64 * 2048;

  bf16x8 qf[4][2];
#pragma unroll
  for (int bi = 0; bi < 4; ++bi)
#pragma unroll
    for (int ks = 0; ks < 2; ++ks)
      qf[bi][ks] = ldfrag(Q + (size_t)(b * 2048 + qw + bi * 16 + ln) * 1024 + h * 64 + ks * 32 + quad * 8);

  floatx4 ot[4][4];
#pragma unroll
  for (int ai = 0; ai < 4; ++ai)
#pragma unroll
    for (int bi = 0; bi < 4; ++bi) ot[ai][bi] = floatx4{0.f, 0.f, 0.f, 0.f};
  float li[4] = {0.f, 0.f, 0.f, 0.f};

  for (int t = wave; t < ntiles; t += 2) {
    const int kv0 = t * 64;
    const bool diag = (t == ntiles - 1);

    // K and V^T A-frags: straight global->VGPR, issued together up front
    const ushort_t* kp = kbase + (size_t)(kv0 + ln) * 1024 + quad * 8;
    bf16x8 kf[4][2];
#pragma unroll
    for (int mi = 0; mi < 4; ++mi)
#pragma unroll
      for (int ks = 0; ks < 2; ++ks)
        kf[mi][ks] = ldfrag(kp + mi * 16 * 1024 + ks * 32);

    const ushort_t* vp = vbase + (size_t)ln * 2048 + kv0 + quad * 8;
    bf16x8 vf[4][2];
#pragma unroll
    for (int ai = 0; ai < 4; ++ai)
#pragma unroll
      for (int ks = 0; ks < 2; ++ks)
        vf[ai][ks] = ldfrag(vp + ai * 16 * 2048 + ks * 32);

    // per-bi: S-MFMA -> softmax -> transform -> PV  (small live ranges)
#pragma unroll
    for (int bi = 0; bi < 4; ++bi) {
      floatx4 st[4];
#pragma unroll
      for (int mi = 0; mi < 4; ++mi) st[mi] = floatx4{0.f, 0.f, 0.f, 0.f};
#pragma unroll
      for (int mi = 0; mi < 4; ++mi) {
        st[mi] = __builtin_amdgcn_mfma_f32_16x16x32_bf16(kf[mi][0], qf[bi][0], st[mi], 0, 0, 0);
        st[mi] = __builtin_amdgcn_mfma_f32_16x16x32_bf16(kf[mi][1], qf[bi][1], st[mi], 0, 0, 0);
      }

      const int qrow = qw + bi * 16 + ln;
      float p[4][4];
      if (diag) {
#pragma unroll
        for (int mi = 0; mi < 4; ++mi)
#pragma unroll
          for (int r = 0; r < 4; ++r) {
            const int kv = kv0 + mi * 16 + quad * 4 + r;
            const float e = __builtin_amdgcn_exp2f(st[mi][r]);
            p[mi][r] = (kv > qrow) ? 0.f : e;
          }
      } else {
#pragma unroll
        for (int mi = 0; mi < 4; ++mi)
#pragma unroll
          for (int r = 0; r < 4; ++r) p[mi][r] = __builtin_amdgcn_exp2f(st[mi][r]);
      }

      unsigned d[4][2];
#pragma unroll
      for (int mi = 0; mi < 4; ++mi) {
        li[bi] += (p[mi][0] + p[mi][1]) + (p[mi][2] + p[mi][3]);
        d[mi][0] = __builtin_amdgcn_perm(
            __builtin_bit_cast(unsigned, p[mi][1]), __builtin_bit_cast(unsigned, p[mi][0]), 0x07060302u);
        d[mi][1] = __builtin_amdgcn_perm(
            __builtin_bit_cast(unsigned, p[mi][3]), __builtin_bit_cast(unsigned, p[mi][2]), 0x07060302u);
      }

      bf16x8 pb[2];
#pragma unroll
      for (int ks = 0; ks < 2; ++ks) {
        uintx4 w;
#pragma unroll
        for (int jj = 0; jj < 4; ++jj) {
          const int idx = (jj >> 1) ? idxB : idxA;
          const int lo = __builtin_amdgcn_ds_bpermute(idx, (int)d[2 * ks][jj & 1]);
          const int hi = __builtin_amdgcn_ds_bpermute(idx, (int)d[2 * ks + 1][jj & 1]);
          w[jj] = (unsigned)(hiq ? hi : lo);
        }
        pb[ks] = __builtin_bit_cast(bf16x8, w);
      }

#pragma unroll
      for (int ai = 0; ai < 4; ++ai) {
        ot[ai][bi] = __builtin_amdgcn_mfma_f32_16x16x32_bf16(vf[ai][0], pb[0], ot[ai][bi], 0, 0, 0);
        ot[ai][bi] = __builtin_amdgcn_mfma_f32_16x16x32_bf16(vf[ai][1], pb[1], ot[ai][bi], 0, 0, 0);
      }
    }
  }

  // cross-wave additive combine (both waves own the same q-rows)
  if (wave == 1) {
#pragma unroll
    for (int bi = 0; bi < 4; ++bi) {
#pragma unroll
      for (int ai = 0; ai < 4; ++ai)
        *(floatx4*)&Cb[bi * 16 + ln][ai * 16 + quad * 4] = ot[ai][bi];
      lbuf[bi * 16 + ln][quad] = 0.f;  // placeholder to keep shape; real li below
    }
#pragma unroll
    for (int bi = 0; bi < 4; ++bi) lbuf[lane][bi] = li[bi];
  }
  __syncthreads();
  if (wave == 0) {
#pragma unroll
    for (int bi = 0; bi < 4; ++bi) {
#pragma unroll
      for (int ai = 0; ai < 4; ++ai) {
        const floatx4 o = *(const floatx4*)&Cb[bi * 16 + ln][ai * 16 + quad * 4];
#pragma unroll
        for (int r = 0; r < 4; ++r) ot[ai][bi][r] += o[r];
      }
      li[bi] += lbuf[lane][bi];
    }

#pragma unroll
    for (int bi = 0; bi < 4; ++bi) {
      li[bi] += __shfl_xor(li[bi], 16);
      li[bi] += __shfl_xor(li[bi], 32);
      const float inv = 1.0f / li[bi];
      const int qrow = qw + bi * 16 + ln;
      if (f32o) {
        float* of = (float*)out;
#pragma unroll
        for (int ai = 0; ai < 4; ++ai) {
          floatx4 o;
#pragma unroll
          for (int r = 0; r < 4; ++r) o[r] = ot[ai][bi][r] * inv;
          *(floatx4*)(of + (size_t)(b * 2048 + qrow) * 1024 + h * 64 + ai * 16 + quad * 4) = o;
        }
      } else {
        ushort_t* ob = (ushort_t*)out;
#pragma unroll
        for (int ai = 0; ai < 4; ++ai) {
          ushortx4 pk;
#pragma unroll
          for (int r = 0; r < 4; ++r) pk[r] = f2bf(ot[ai][bi][r] * inv);
          *(ushortx4*)(ob + (size_t)(b * 2048 + qrow) * 1024 + h * 64 + ai * 16 + quad * 4) = pk;
        }
      }
    }
  }
}

// ---------------------------------------------------------------------------
extern "C" void kernel_launch(void* const* d_in, const int* in_sizes, int n_in,
                              void* d_out, int out_size, void* d_ws, size_t ws_size,
                              hipStream_t stream) {
  char* w = (char*)d_ws;
  int* flag = (int*)w;
  size_t off = 256;
  ushort_t* xb  = (ushort_t*)(w + off); off += (size_t)4194304 * 2;
  ushort_t* wqb = (ushort_t*)(w + off); off += (size_t)1048576 * 2;
  ushort_t* wkb = (ushort_t*)(w + off); off += (size_t)1048576 * 2;
  ushort_t* wvb = (ushort_t*)(w + off); off += (size_t)1048576 * 2;
  float* biasf  = (float*)(w + off);    off += (size_t)3 * 1024 * 4;
  ushort_t* Qw  = (ushort_t*)(w + off); off += (size_t)4194304 * 2;
  ushort_t* Kw  = (ushort_t*)(w + off); off += (size_t)4194304 * 2;
  ushort_t* Vtw = (ushort_t*)(w + off);

  convert_all<<<dim3(2048, 5), 256, 0, stream>>>(
      d_in[0], d_in[1], d_in[3], d_in[5], d_in[2], d_in[4], d_in[6],
      xb, wqb, wkb, wvb, biasf, flag);
  qkv_gemm<<<dim3(8, 32, 3), 256, 0, stream>>>(xb, wqb, wkb, wvb, biasf, Qw, Kw, Vtw);
  flash8<<<1024, 128, 0, stream>>>(Qw, Kw, Vtw, d_out, flag);
}